// Round 4
// baseline (559.541 us; speedup 1.0000x reference)
//
#include <hip/hip_runtime.h>
#include <hip/hip_bf16.h>
#include <math.h>

// Problem constants
#define B_  8
#define L_  128
#define V_  32000
#define D_  64
#define R1_ 128
#define R2_ 320
#define UP_ 640
#define SPLITS_ 100   // k-splits for stage A (320 k each)

typedef short bf16x8 __attribute__((ext_vector_type(8)));
typedef float f32x4 __attribute__((ext_vector_type(4)));

#define GLDS16(gp, lp)                                                         \
    __builtin_amdgcn_global_load_lds(                                          \
        (const __attribute__((address_space(1))) void*)(gp),                   \
        (__attribute__((address_space(3))) void*)(lp), 16, 0, 0)

static __device__ inline unsigned short f2bf(float x) {
    __hip_bfloat16 h = __float2bfloat16(x);
    return *reinterpret_cast<unsigned short*>(&h);
}

// hi/lo bf16 split: v ~= hi + lo with rel err ~2^-17
static __device__ inline void split1(float v, unsigned short& h, unsigned short& l) {
    unsigned short hb = f2bf(v);
    float hf = __uint_as_float(((unsigned int)hb) << 16);
    h = hb;
    l = f2bf(v - hf);
}

// ---------------------------------------------------------------------------
// transpose_f32: dst[C][R] = src[R][C]^T ; writes coalesced, reads strided (L2)
__global__ __launch_bounds__(256) void transpose_f32(const float* __restrict__ src,
                                                     float* __restrict__ dst,
                                                     int R, int C) {
    int idx = blockIdx.x * 256 + threadIdx.x;
    if (idx < R * C) {
        int c = idx / R, r = idx - c * R;
        dst[idx] = src[(size_t)r * C + c];
    }
}

// ---------------------------------------------------------------------------
// convW_emb: W_emb[64][32000] fp32 -> k-blocked bf16 hi/lo:
//   Whb/Wlb unit u = kb*64 + row holds rows' k-range [kb*8, kb*8+8) (16 B)
__global__ __launch_bounds__(256) void convW_emb(const float* __restrict__ Wemb,
                                                 unsigned short* __restrict__ Whb,
                                                 unsigned short* __restrict__ Wlb) {
    int u = blockIdx.x * 256 + threadIdx.x;   // 0 .. 64*4000-1
    int kb = u >> 6, row = u & 63;
    const float* s = Wemb + (size_t)row * 32000 + kb * 8;
    unsigned short h8[8], l8[8];
#pragma unroll
    for (int j = 0; j < 8; ++j) split1(s[j], h8[j], l8[j]);
    *(ushort4*)&Whb[(size_t)u * 8]     = *(ushort4*)&h8[0];
    *(ushort4*)&Whb[(size_t)u * 8 + 4] = *(ushort4*)&h8[4];
    *(ushort4*)&Wlb[(size_t)u * 8]     = *(ushort4*)&l8[0];
    *(ushort4*)&Wlb[(size_t)u * 8 + 4] = *(ushort4*)&l8[4];
}

// ---------------------------------------------------------------------------
// pe_kernel v2: out[l,o] = relu(b[o] + sum_m P[l,m]*WT[m,o]); WT pre-transposed
// grid: 128 (l), block: outF threads (64/128/320)
__global__ __launch_bounds__(320) void pe_kernel(const float* __restrict__ WT,
                                                 const float* __restrict__ bias,
                                                 float* __restrict__ out,
                                                 int outF, int dEnc) {
    __shared__ float P[640];
    int l = blockIdx.x;
    int t = threadIdx.x;
    for (int m = t; m < dEnc; m += outF) {
        int i = m >> 1;
        float ang = (float)l * powf(10000.0f, -2.0f * (float)i / (float)dEnc);
        P[m] = (m & 1) ? cosf(ang) : sinf(ang);
    }
    __syncthreads();
    float acc = bias[t];
#pragma unroll 4
    for (int m = 0; m < dEnc; ++m) acc = fmaf(P[m], WT[(size_t)m * outF + t], acc);
    out[l * outF + t] = fmaxf(acc, 0.f);
}

// ---------------------------------------------------------------------------
// Stage A via MFMA, 3-product bf16 split, software-pipelined.
// partA[split][row][d] = sum_{k in split} x[row,k]*W_emb[d,k]
// grid: (16 rowblocks of 64, SPLITS_), block 256 (4 waves; wave w -> x-rows 16w..16w+15)
// LDS: double-buffered W tiles, 16 KB each: [Wh: (g*64+n)*16B][Wl: +8192]
// W staged by GLDS16 from pre-split blocked Whb/Wlb (no VALU, contiguous lanes);
// x prefetched to VGPRs one chunk ahead and split in-register into A-frags.
__global__ __launch_bounds__(256) void embA_mfma(const float* __restrict__ x,
                                                 const unsigned short* __restrict__ Whb,
                                                 const unsigned short* __restrict__ Wlb,
                                                 float* __restrict__ partA) {
    __shared__ short lds[16384];   // 32 KB = 2 buffers x 16 KB
    int t = threadIdx.x;
    int lane = t & 63, w = t >> 6;
    int ln = lane & 15, lg = lane >> 4;
    int rb = blockIdx.x, ks = blockIdx.y;
    int row0 = rb * 64;
    const float* xrow = x + (size_t)(row0 + w * 16 + ln) * 32000;

    f32x4 acc[4];
#pragma unroll
    for (int nt = 0; nt < 4; ++nt) acc[nt] = (f32x4){0.f, 0.f, 0.f, 0.f};

    float4 xc[4], xn[4];

    // --- stage chunk 0 (W -> buf0) + load x chunk 0 ---
    {
        int kb0 = (ks * 320) >> 3;
#pragma unroll
        for (int s = 0; s < 4; ++s) {
            int ubase = s * 256 + w * 64;
            const unsigned short* arr = (s < 2) ? Whb : Wlb;
            int uu = (s < 2) ? ubase : (ubase - 512);
            const char* gp = (const char*)arr + ((size_t)kb0 * 64 + uu + lane) * 16;
            char* lp = (char*)lds + ((s < 2) ? 0 : 8192) + uu * 16;
            GLDS16(gp, lp);
        }
        const float* bp = xrow + ks * 320 + lg * 8;
        xc[0] = ((const float4*)bp)[0];
        xc[1] = ((const float4*)bp)[1];
        xc[2] = ((const float4*)(bp + 32))[0];
        xc[3] = ((const float4*)(bp + 32))[1];
    }

#pragma unroll
    for (int ch = 0; ch < 5; ++ch) {
        __syncthreads();   // drains chunk-ch GLDS16 + x loads (vmcnt0 before barrier)
        if (ch < 4) {      // kick chunk ch+1 into the other buffer; full compute to land
            int kb0 = (ks * 320 + (ch + 1) * 64) >> 3;
            int p = (ch + 1) & 1;
#pragma unroll
            for (int s = 0; s < 4; ++s) {
                int ubase = s * 256 + w * 64;
                const unsigned short* arr = (s < 2) ? Whb : Wlb;
                int uu = (s < 2) ? ubase : (ubase - 512);
                const char* gp = (const char*)arr + ((size_t)kb0 * 64 + uu + lane) * 16;
                char* lp = (char*)lds + p * 16384 + ((s < 2) ? 0 : 8192) + uu * 16;
                GLDS16(gp, lp);
            }
            const float* bp = xrow + ks * 320 + (ch + 1) * 64 + lg * 8;
            xn[0] = ((const float4*)bp)[0];
            xn[1] = ((const float4*)bp)[1];
            xn[2] = ((const float4*)(bp + 32))[0];
            xn[3] = ((const float4*)(bp + 32))[1];
        }
        // split current x into A-fragments (in-register)
        bf16x8 ah[2], al[2];
#pragma unroll
        for (int kstep = 0; kstep < 2; ++kstep) {
            float f[8] = {xc[2 * kstep].x, xc[2 * kstep].y, xc[2 * kstep].z, xc[2 * kstep].w,
                          xc[2 * kstep + 1].x, xc[2 * kstep + 1].y, xc[2 * kstep + 1].z,
                          xc[2 * kstep + 1].w};
            unsigned short h8[8], l8[8];
#pragma unroll
            for (int j = 0; j < 8; ++j) split1(f[j], h8[j], l8[j]);
            ah[kstep] = *(bf16x8*)h8;
            al[kstep] = *(bf16x8*)l8;
        }
        const char* buf = (const char*)lds + (ch & 1) * 16384;
#pragma unroll
        for (int kstep = 0; kstep < 2; ++kstep) {
            int g = kstep * 4 + lg;
#pragma unroll
            for (int nt = 0; nt < 4; ++nt) {
                int nrow = nt * 16 + ln;
                bf16x8 bh = *(const bf16x8*)(buf + (g * 64 + nrow) * 16);
                bf16x8 bl = *(const bf16x8*)(buf + 8192 + (g * 64 + nrow) * 16);
                acc[nt] = __builtin_amdgcn_mfma_f32_16x16x32_bf16(ah[kstep], bh, acc[nt], 0, 0, 0);
                acc[nt] = __builtin_amdgcn_mfma_f32_16x16x32_bf16(ah[kstep], bl, acc[nt], 0, 0, 0);
                acc[nt] = __builtin_amdgcn_mfma_f32_16x16x32_bf16(al[kstep], bh, acc[nt], 0, 0, 0);
            }
        }
#pragma unroll
        for (int i = 0; i < 4; ++i) xc[i] = xn[i];
    }
    // C/D: col(n=d)=lane&15, row(m=x-row)=(lane>>4)*4+reg
#pragma unroll
    for (int nt = 0; nt < 4; ++nt)
#pragma unroll
        for (int r = 0; r < 4; ++r)
            partA[((size_t)ks * 1024 + row0 + w * 16 + lg * 4 + r) * 64 + nt * 16 + ln] =
                acc[nt][r];
}

// ---------------------------------------------------------------------------
// reduceA: h1[row,d] = relu(sum_s partA + b_emb[d]) + pe1[l,d]; s1[row]=sum_d h1
__global__ __launch_bounds__(64) void reduceA_kernel(const float* __restrict__ partA,
                                                     const float* __restrict__ bemb,
                                                     const float* __restrict__ pe1,
                                                     float* __restrict__ h1,
                                                     float* __restrict__ s1) {
    int row = blockIdx.x;
    int d = threadIdx.x;
    int l = row & 127;
    float v = bemb[d];
#pragma unroll 4
    for (int s = 0; s < SPLITS_; ++s) v += partA[((size_t)s * 1024 + row) * 64 + d];
    v = fmaxf(v, 0.f) + pe1[l * 64 + d];
    h1[row * 64 + d] = v;
    float sum = v;
    for (int off = 32; off > 0; off >>= 1) sum += __shfl_down(sum, off);
    if (d == 0) s1[row] = sum;
}

// ---------------------------------------------------------------------------
// wr1: Wr1[b,r,j] = sum_k s1[b,k] * W_red[r, k*64+j]
__global__ __launch_bounds__(64) void wr1_kernel(const float* __restrict__ Wred,
                                                 const float* __restrict__ s1,
                                                 float* __restrict__ Wr1) {
    __shared__ float ss[8 * 128];
    int r = blockIdx.x;
    int j = threadIdx.x;
    for (int idx = j; idx < 1024; idx += 64) ss[idx] = s1[idx];
    __syncthreads();
    float acc[8];
#pragma unroll
    for (int b = 0; b < 8; ++b) acc[b] = 0.f;
    const float* w = Wred + (size_t)r * 8192 + j;
    for (int k = 0; k < 128; ++k) {
        float wv = w[k * 64];
#pragma unroll
        for (int b = 0; b < 8; ++b) acc[b] = fmaf(ss[b * 128 + k], wv, acc[b]);
    }
#pragma unroll
    for (int b = 0; b < 8; ++b) Wr1[((size_t)b * 128 + r) * 64 + j] = acc[b];
}

// ---------------------------------------------------------------------------
// h2: h2[b,i,r] = relu(sum_j h1[b,i,j]*Wr1[b,r,j] + b_red[r]) + pe2[i,r]; s2=sum_r
__global__ __launch_bounds__(128) void h2_kernel(const float* __restrict__ h1,
                                                 const float* __restrict__ Wr1,
                                                 const float* __restrict__ bred,
                                                 const float* __restrict__ pe2,
                                                 float* __restrict__ h2,
                                                 float* __restrict__ s2) {
    __shared__ float hrow[64];
    __shared__ float red[2];
    int row = blockIdx.x;
    int b = row >> 7, i = row & 127;
    int r = threadIdx.x;
    if (r < 64) hrow[r] = h1[row * 64 + r];
    __syncthreads();
    float acc = bred[r];
    const float4* w = (const float4*)(Wr1 + ((size_t)b * 128 + r) * 64);
#pragma unroll
    for (int j4 = 0; j4 < 16; ++j4) {
        float4 wv = w[j4];
        float4 hv = *(const float4*)&hrow[j4 * 4];
        acc = fmaf(hv.x, wv.x, acc);
        acc = fmaf(hv.y, wv.y, acc);
        acc = fmaf(hv.z, wv.z, acc);
        acc = fmaf(hv.w, wv.w, acc);
    }
    float val = fmaxf(acc, 0.f) + pe2[i * 128 + r];
    h2[row * 128 + r] = val;
    float sum = val;
    for (int off = 32; off > 0; off >>= 1) sum += __shfl_down(sum, off);
    if ((r & 63) == 0) red[r >> 6] = sum;
    __syncthreads();
    if (r == 0) s2[row] = red[0] + red[1];
}

// ---------------------------------------------------------------------------
// wr2: Wr2[b,r2,j] = sum_k s2[b,k] * W_red2[r2, k*128+j]
__global__ __launch_bounds__(128) void wr2_kernel(const float* __restrict__ Wred2,
                                                  const float* __restrict__ s2,
                                                  float* __restrict__ Wr2) {
    __shared__ float ss[8 * 128];
    int r = blockIdx.x;
    int j = threadIdx.x;
    for (int idx = j; idx < 1024; idx += 128) ss[idx] = s2[idx];
    __syncthreads();
    float acc[8];
#pragma unroll
    for (int b = 0; b < 8; ++b) acc[b] = 0.f;
    const float* w = Wred2 + (size_t)r * 16384 + j;
    for (int k = 0; k < 128; ++k) {
        float wv = w[k * 128];
#pragma unroll
        for (int b = 0; b < 8; ++b) acc[b] = fmaf(ss[b * 128 + k], wv, acc[b]);
    }
#pragma unroll
    for (int b = 0; b < 8; ++b) Wr2[((size_t)b * 320 + r) * 128 + j] = acc[b];
}

// ---------------------------------------------------------------------------
// h3: h3[b,i,r2] = relu(sum_j h2[b,i,j]*Wr2[b,r2,j] + b_red2[r2]) + pe3[i,r2]
__global__ __launch_bounds__(320) void h3_kernel(const float* __restrict__ h2,
                                                 const float* __restrict__ Wr2,
                                                 const float* __restrict__ bred2,
                                                 const float* __restrict__ pe3,
                                                 float* __restrict__ h3) {
    __shared__ float hrow[128];
    int row = blockIdx.x;
    int b = row >> 7, i = row & 127;
    int r = threadIdx.x;
    if (r < 128) hrow[r] = h2[row * 128 + r];
    __syncthreads();
    float acc = bred2[r];
    const float4* w = (const float4*)(Wr2 + ((size_t)b * 320 + r) * 128);
#pragma unroll
    for (int j4 = 0; j4 < 32; ++j4) {
        float4 wv = w[j4];
        float4 hv = *(const float4*)&hrow[j4 * 4];
        acc = fmaf(hv.x, wv.x, acc);
        acc = fmaf(hv.y, wv.y, acc);
        acc = fmaf(hv.z, wv.z, acc);
        acc = fmaf(hv.w, wv.w, acc);
    }
    h3[(size_t)row * 320 + r] = fmaxf(acc, 0.f) + pe3[i * 320 + r];
}

// ---------------------------------------------------------------------------
// h4 v2: h4b[row,u] = bf16(relu(sum_k h3[row,k]*Wup1T[k,u] + b_up1[u]))
// grid: (256 rowgroups of 4, 2 u-halves), block 320 (thread = one u)
// Wup1T reads lane-coalesced; h3 rows broadcast from LDS (hsT[j][q]).
__global__ __launch_bounds__(320) void h4_kernel(const float* __restrict__ h3,
                                                 const float* __restrict__ Wup1T,
                                                 const float* __restrict__ bup1,
                                                 unsigned short* __restrict__ h4b) {
    __shared__ float hsT[320 * 4];
    int t = threadIdx.x;
    int row0 = blockIdx.x * 4;
    int u = blockIdx.y * 320 + t;
    for (int idx = t; idx < 1280; idx += 320) {
        int q = idx / 320, j = idx - q * 320;
        hsT[j * 4 + q] = h3[(size_t)(row0 + q) * 320 + j];
    }
    __syncthreads();
    float acc[4] = {0.f, 0.f, 0.f, 0.f};
    const float* wt = Wup1T + u;
#pragma unroll 4
    for (int j = 0; j < 320; ++j) {
        float wv = wt[(size_t)j * 640];
        float4 hv = *(const float4*)&hsT[j * 4];
        acc[0] = fmaf(hv.x, wv, acc[0]);
        acc[1] = fmaf(hv.y, wv, acc[1]);
        acc[2] = fmaf(hv.z, wv, acc[2]);
        acc[3] = fmaf(hv.w, wv, acc[3]);
    }
    float bias = bup1[u];
#pragma unroll
    for (int q = 0; q < 4; ++q)
        h4b[(size_t)(row0 + q) * 640 + u] = f2bf(fmaxf(acc[q] + bias, 0.f));
}

// ---------------------------------------------------------------------------
// conv_bf16: fp32 -> bf16, vectorized (float4 in, ushort4 out)
__global__ __launch_bounds__(256) void conv_bf16(const float* __restrict__ src,
                                                 unsigned short* __restrict__ dst,
                                                 int n4) {
    int stride = gridDim.x * 256;
    for (int i = blockIdx.x * 256 + threadIdx.x; i < n4; i += stride) {
        float4 v = ((const float4*)src)[i];
        ushort4 o;
        o.x = f2bf(v.x); o.y = f2bf(v.y); o.z = f2bf(v.z); o.w = f2bf(v.w);
        ((ushort4*)dst)[i] = o;
    }
}

// ---------------------------------------------------------------------------
// final MFMA kernel:
// out[b,v] = relu(bfin + sum_l Wfin[l]*relu(bup2[v] + sum_u h4[b,l,u]*Wup2[v,u]))
__global__ __launch_bounds__(256) void final_mfma_kernel(
    const unsigned short* __restrict__ h4b,
    const unsigned short* __restrict__ Wup2b,
    const float* __restrict__ bup2,
    const float* __restrict__ Wfin,
    const float* __restrict__ bfin,
    float* __restrict__ out) {
    __shared__ short tile[16384];   // A: bytes [0,16384), B: bytes [16384,32768)
    __shared__ float redbuf[256];

    int t = threadIdx.x;
    int lane = t & 63;
    int w = t >> 6;
    int wv = w >> 1, wl = w & 1;
    int ln = lane & 15, lg = lane >> 4;
    int b = blockIdx.y;
    int v0 = blockIdx.x * 128;

    const char* Ag = (const char*)Wup2b;
    const char* Bg = (const char*)h4b;
    bool isA = (w < 2);
    int seg = (isA ? w : (w - 2)) * 8192;  // byte offset within 16KB half

    f32x4 acc[4][4];
#pragma unroll
    for (int mt = 0; mt < 4; ++mt)
#pragma unroll
        for (int nt = 0; nt < 4; ++nt) acc[mt][nt] = (f32x4){0.f, 0.f, 0.f, 0.f};

    for (int ch = 0; ch < 10; ++ch) {
        int k0 = ch * 64;
        __syncthreads();
#pragma unroll
        for (int s = 0; s < 8; ++s) {
            int F = seg + s * 1024 + lane * 16;       // byte offset in half
            int r = F >> 7;                            // row 0..127
            int g = ((F >> 4) & 7) ^ (r & 7);          // logical k-block
            size_t rowG = isA ? (size_t)(v0 + r) : (size_t)(b * 128 + r);
            const char* gp = (isA ? Ag : Bg) + (rowG * 640 + (size_t)(k0 + g * 8)) * 2;
            char* lp = (char*)tile + (isA ? 0 : 16384) + seg + s * 1024;  // uniform
            GLDS16(gp, lp);
        }
        __syncthreads();
#pragma unroll
        for (int ks = 0; ks < 2; ++ks) {
            bf16x8 aF[4], bF[4];
#pragma unroll
            for (int mt = 0; mt < 4; ++mt) {
                int rA = wv * 64 + mt * 16 + ln;
                int g = ks * 4 + lg;
                int off = rA * 128 + ((g ^ (rA & 7)) * 16);
                aF[mt] = *(const bf16x8*)((const char*)tile + off);
            }
#pragma unroll
            for (int nt = 0; nt < 4; ++nt) {
                int rB = wl * 64 + nt * 16 + ln;
                int g = ks * 4 + lg;
                int off = 16384 + rB * 128 + ((g ^ (rB & 7)) * 16);
                bF[nt] = *(const bf16x8*)((const char*)tile + off);
            }
#pragma unroll
            for (int mt = 0; mt < 4; ++mt)
#pragma unroll
                for (int nt = 0; nt < 4; ++nt)
                    acc[mt][nt] = __builtin_amdgcn_mfma_f32_16x16x32_bf16(
                        aF[mt], bF[nt], acc[mt][nt], 0, 0, 0);
        }
    }

    // Epilogue: C/D layout col(l)=lane&15, row(v)=(lane>>4)*4+reg
    float bfin0 = bfin[0];
#pragma unroll
    for (int mt = 0; mt < 4; ++mt) {
        float bu[4];
#pragma unroll
        for (int r = 0; r < 4; ++r)
            bu[r] = bup2[v0 + wv * 64 + mt * 16 + lg * 4 + r];
        float part[4] = {0.f, 0.f, 0.f, 0.f};
#pragma unroll
        for (int nt = 0; nt < 4; ++nt) {
            float wf = Wfin[wl * 64 + nt * 16 + ln];
#pragma unroll
            for (int r = 0; r < 4; ++r)
                part[r] += wf * fmaxf(acc[mt][nt][r] + bu[r], 0.f);
        }
#pragma unroll
        for (int off = 8; off >= 1; off >>= 1)
#pragma unroll
            for (int r = 0; r < 4; ++r) part[r] += __shfl_xor(part[r], off, 64);
        if (ln == 0) {
#pragma unroll
            for (int r = 0; r < 4; ++r)
                redbuf[wl * 128 + wv * 64 + mt * 16 + lg * 4 + r] = part[r];
        }
    }
    __syncthreads();
    if (t < 128) {
        float vsum = redbuf[t] + redbuf[128 + t] + bfin0;
        out[(size_t)b * 32000 + v0 + t] = fmaxf(vsum, 0.f);
    }
}

// ---------------------------------------------------------------------------
extern "C" void kernel_launch(void* const* d_in, const int* in_sizes, int n_in,
                              void* d_out, int out_size, void* d_ws, size_t ws_size,
                              hipStream_t stream) {
    const float* x      = (const float*)d_in[0];
    const float* W_emb  = (const float*)d_in[1];
    const float* b_emb  = (const float*)d_in[2];
    const float* W_pos1 = (const float*)d_in[3];
    const float* b_pos1 = (const float*)d_in[4];
    const float* W_red  = (const float*)d_in[5];
    const float* b_red  = (const float*)d_in[6];
    const float* W_pos2 = (const float*)d_in[7];
    const float* b_pos2 = (const float*)d_in[8];
    const float* W_red2 = (const float*)d_in[9];
    const float* b_red2 = (const float*)d_in[10];
    const float* W_pos3 = (const float*)d_in[11];
    const float* b_pos3 = (const float*)d_in[12];
    const float* W_up1  = (const float*)d_in[13];
    const float* b_up1  = (const float*)d_in[14];
    const float* W_up2  = (const float*)d_in[15];
    const float* b_up2  = (const float*)d_in[16];
    const float* W_fin  = (const float*)d_in[17];
    const float* b_fin  = (const float*)d_in[18];
    float* out = (float*)d_out;

    float* ws  = (float*)d_ws;
    float* pe1 = ws;                 // 8192
    float* pe2 = pe1 + 8192;         // 16384
    float* pe3 = pe2 + 16384;        // 40960
    float* h1  = pe3 + 40960;        // 65536
    float* s1  = h1 + 65536;         // 1024
    float* Wr1 = s1 + 1024;          // 65536
    float* h2  = Wr1 + 65536;        // 131072
    float* s2  = h2 + 131072;        // 1024
    float* Wr2 = s2 + 1024;          // 327680
    float* h3  = Wr2 + 327680;       // 327680
    unsigned short* h4b   = (unsigned short*)(h3 + 327680);          // 655360 shorts
    unsigned short* Wup2b = (unsigned short*)((float*)h4b + 327680); // 20,480,000 shorts
    float* after = (float*)Wup2b + 10240000;
    float* WposT1 = after;            // 8192
    float* WposT2 = WposT1 + 8192;    // 32768
    float* WposT3 = WposT2 + 32768;   // 204800
    float* Wup1T  = WposT3 + 204800;  // 204800
    unsigned short* Whb = (unsigned short*)(Wup1T + 204800);  // 2,048,000 shorts
    unsigned short* Wlb = Whb + 2048000;                      // 2,048,000 shorts
    // partA (100*1024*64 = 6.55M floats = 26.2 MB) aliases the Wup2b region
    // (dead after reduceA; conv_bf16 writes Wup2b later).
    float* partA = (float*)Wup2b;
    // total ws use ~56 MB

    // one-time-per-launch weight preprocessing
    convW_emb<<<dim3(1000), 256, 0, stream>>>(W_emb, Whb, Wlb);
    transpose_f32<<<dim3(32), 256, 0, stream>>>(W_pos1, WposT1, 64, 128);
    transpose_f32<<<dim3(128), 256, 0, stream>>>(W_pos2, WposT2, 128, 256);
    transpose_f32<<<dim3(800), 256, 0, stream>>>(W_pos3, WposT3, 320, 640);
    transpose_f32<<<dim3(800), 256, 0, stream>>>(W_up1, Wup1T, 640, 320);

    pe_kernel<<<dim3(128), 64, 0, stream>>>(WposT1, b_pos1, pe1, 64, 128);
    pe_kernel<<<dim3(128), 128, 0, stream>>>(WposT2, b_pos2, pe2, 128, 256);
    pe_kernel<<<dim3(128), 320, 0, stream>>>(WposT3, b_pos3, pe3, 320, 640);

    embA_mfma<<<dim3(16, SPLITS_), 256, 0, stream>>>(x, Whb, Wlb, partA);
    reduceA_kernel<<<dim3(1024), 64, 0, stream>>>(partA, b_emb, pe1, h1, s1);
    conv_bf16<<<dim3(4096), 256, 0, stream>>>(W_up2, Wup2b, (V_ * UP_) / 4);
    wr1_kernel<<<dim3(128), 64, 0, stream>>>(W_red, s1, Wr1);
    h2_kernel<<<dim3(1024), 128, 0, stream>>>(h1, Wr1, b_red, pe2, h2, s2);
    wr2_kernel<<<dim3(320), 128, 0, stream>>>(W_red2, s2, Wr2);
    h3_kernel<<<dim3(1024), 320, 0, stream>>>(h2, Wr2, b_red2, pe3, h3);
    h4_kernel<<<dim3(256, 2), 320, 0, stream>>>(h3, Wup1T, b_up1, h4b);
    final_mfma_kernel<<<dim3(250, 8), 256, 0, stream>>>(h4b, Wup2b, b_up2, W_fin,
                                                        b_fin, out);
}

// Round 5
// 472.789 us; speedup vs baseline: 1.1835x; 1.1835x over previous
//
#include <hip/hip_runtime.h>
#include <hip/hip_bf16.h>
#include <math.h>

// Problem constants
#define B_  8
#define L_  128
#define V_  32000
#define D_  64
#define R1_ 128
#define R2_ 320
#define UP_ 640
#define SPLITS_ 50   // k-splits for stage A (640 k each)

typedef short bf16x8 __attribute__((ext_vector_type(8)));
typedef float f32x4 __attribute__((ext_vector_type(4)));

#define GLDS16(gp, lp)                                                         \
    __builtin_amdgcn_global_load_lds(                                          \
        (const __attribute__((address_space(1))) void*)(gp),                   \
        (__attribute__((address_space(3))) void*)(lp), 16, 0, 0)

static __device__ inline unsigned short f2bf(float x) {
    __hip_bfloat16 h = __float2bfloat16(x);
    return *reinterpret_cast<unsigned short*>(&h);
}

// hi/lo bf16 split: v ~= hi + lo with rel err ~2^-17
static __device__ inline void split1(float v, unsigned short& h, unsigned short& l) {
    unsigned short hb = f2bf(v);
    float hf = __uint_as_float(((unsigned int)hb) << 16);
    h = hb;
    l = f2bf(v - hf);
}

// ---------------------------------------------------------------------------
// prep_weights: one launch, two jobs.
//   blocks [0,1000):   W_emb[64][32000] fp32 -> k-blocked bf16 hi/lo
//                      (unit u = kb*64+row holds that row's k-range [kb*8,kb*8+8))
//   blocks [1000,5096): Wup2 fp32 -> bf16 (grid-stride over float4s)
__global__ __launch_bounds__(256) void prep_weights(const float* __restrict__ Wemb,
                                                    unsigned short* __restrict__ Whb,
                                                    unsigned short* __restrict__ Wlb,
                                                    const float* __restrict__ Wup2,
                                                    unsigned short* __restrict__ Wup2b) {
    int bx = blockIdx.x, t = threadIdx.x;
    if (bx < 1000) {
        int u = bx * 256 + t;   // 0 .. 256000-1
        int kb = u >> 6, row = u & 63;
        const float* s = Wemb + (size_t)row * 32000 + kb * 8;
        unsigned short h8[8], l8[8];
#pragma unroll
        for (int j = 0; j < 8; ++j) split1(s[j], h8[j], l8[j]);
        *(ushort4*)&Whb[(size_t)u * 8]     = *(ushort4*)&h8[0];
        *(ushort4*)&Whb[(size_t)u * 8 + 4] = *(ushort4*)&h8[4];
        *(ushort4*)&Wlb[(size_t)u * 8]     = *(ushort4*)&l8[0];
        *(ushort4*)&Wlb[(size_t)u * 8 + 4] = *(ushort4*)&l8[4];
    } else {
        const int n4 = (V_ * UP_) / 4;
        int stride = 4096 * 256;
        for (int i = (bx - 1000) * 256 + t; i < n4; i += stride) {
            float4 v = ((const float4*)Wup2)[i];
            ushort4 o;
            o.x = f2bf(v.x); o.y = f2bf(v.y); o.z = f2bf(v.z); o.w = f2bf(v.w);
            ((ushort4*)Wup2b)[i] = o;
        }
    }
}

// ---------------------------------------------------------------------------
// pe_all: grid (128 l, 3 stages); out[l,o] = relu(b[o] + sum_m P[l,m]*W[o,m])
// Small L2-resident weights; per-thread row reads are contiguous float4.
__global__ __launch_bounds__(320) void pe_all(const float* __restrict__ W1,
                                              const float* __restrict__ b1,
                                              float* __restrict__ o1,
                                              const float* __restrict__ W2,
                                              const float* __restrict__ b2,
                                              float* __restrict__ o2,
                                              const float* __restrict__ W3,
                                              const float* __restrict__ b3,
                                              float* __restrict__ o3) {
    __shared__ float P[640];
    int l = blockIdx.x;
    int stage = blockIdx.y;
    const float* W = (stage == 0) ? W1 : (stage == 1) ? W2 : W3;
    const float* bias = (stage == 0) ? b1 : (stage == 1) ? b2 : b3;
    float* out = (stage == 0) ? o1 : (stage == 1) ? o2 : o3;
    int outF = (stage == 0) ? 64 : (stage == 1) ? 128 : 320;
    int dEnc = 2 * outF;
    int t = threadIdx.x;
    for (int m = t; m < dEnc; m += 320) {
        int i = m >> 1;
        float ang = (float)l * powf(10000.0f, -2.0f * (float)i / (float)dEnc);
        P[m] = (m & 1) ? cosf(ang) : sinf(ang);
    }
    __syncthreads();
    if (t < outF) {
        float acc = bias[t];
        const float4* w = (const float4*)(W + (size_t)t * dEnc);
        for (int m4 = 0; m4 < dEnc / 4; ++m4) {
            float4 wv = w[m4];
            float4 pv = *(const float4*)&P[m4 * 4];
            acc = fmaf(pv.x, wv.x, acc);
            acc = fmaf(pv.y, wv.y, acc);
            acc = fmaf(pv.z, wv.z, acc);
            acc = fmaf(pv.w, wv.w, acc);
        }
        out[l * outF + t] = fmaxf(acc, 0.f);
    }
}

// ---------------------------------------------------------------------------
// Stage A via MFMA, 3-product bf16 split, software-pipelined (dbuf GLDS16 W,
// VGPR-prefetched x split in-register). partA[split][row][d].
// grid: (16 rowblocks of 64, SPLITS_), block 256.
__global__ __launch_bounds__(256) void embA_mfma(const float* __restrict__ x,
                                                 const unsigned short* __restrict__ Whb,
                                                 const unsigned short* __restrict__ Wlb,
                                                 float* __restrict__ partA) {
    __shared__ short lds[16384];   // 2 x 16 KB
    int t = threadIdx.x;
    int lane = t & 63, w = t >> 6;
    int ln = lane & 15, lg = lane >> 4;
    int rb = blockIdx.x, ks = blockIdx.y;
    int row0 = rb * 64;
    const float* xrow = x + (size_t)(row0 + w * 16 + ln) * 32000;

    f32x4 acc[4];
#pragma unroll
    for (int nt = 0; nt < 4; ++nt) acc[nt] = (f32x4){0.f, 0.f, 0.f, 0.f};

    float4 xc[4], xn[4];
    {
        int kb0 = (ks * 640) >> 3;
#pragma unroll
        for (int s = 0; s < 4; ++s) {
            int ubase = s * 256 + w * 64;
            const unsigned short* arr = (s < 2) ? Whb : Wlb;
            int uu = (s < 2) ? ubase : (ubase - 512);
            const char* gp = (const char*)arr + ((size_t)kb0 * 64 + uu + lane) * 16;
            char* lp = (char*)lds + ((s < 2) ? 0 : 8192) + uu * 16;
            GLDS16(gp, lp);
        }
        const float* bp = xrow + ks * 640 + lg * 8;
        xc[0] = ((const float4*)bp)[0];
        xc[1] = ((const float4*)bp)[1];
        xc[2] = ((const float4*)(bp + 32))[0];
        xc[3] = ((const float4*)(bp + 32))[1];
    }

#pragma unroll 2
    for (int ch = 0; ch < 10; ++ch) {
        __syncthreads();   // drains chunk-ch GLDS16 + x loads
        if (ch < 9) {      // kick chunk ch+1 into the other buffer
            int kb0 = (ks * 640 + (ch + 1) * 64) >> 3;
            int p = (ch + 1) & 1;
#pragma unroll
            for (int s = 0; s < 4; ++s) {
                int ubase = s * 256 + w * 64;
                const unsigned short* arr = (s < 2) ? Whb : Wlb;
                int uu = (s < 2) ? ubase : (ubase - 512);
                const char* gp = (const char*)arr + ((size_t)kb0 * 64 + uu + lane) * 16;
                char* lp = (char*)lds + p * 16384 + ((s < 2) ? 0 : 8192) + uu * 16;
                GLDS16(gp, lp);
            }
            const float* bp = xrow + ks * 640 + (ch + 1) * 64 + lg * 8;
            xn[0] = ((const float4*)bp)[0];
            xn[1] = ((const float4*)bp)[1];
            xn[2] = ((const float4*)(bp + 32))[0];
            xn[3] = ((const float4*)(bp + 32))[1];
        }
        bf16x8 ah[2], al[2];
#pragma unroll
        for (int kstep = 0; kstep < 2; ++kstep) {
            float f[8] = {xc[2 * kstep].x, xc[2 * kstep].y, xc[2 * kstep].z, xc[2 * kstep].w,
                          xc[2 * kstep + 1].x, xc[2 * kstep + 1].y, xc[2 * kstep + 1].z,
                          xc[2 * kstep + 1].w};
            unsigned short h8[8], l8[8];
#pragma unroll
            for (int j = 0; j < 8; ++j) split1(f[j], h8[j], l8[j]);
            ah[kstep] = *(bf16x8*)h8;
            al[kstep] = *(bf16x8*)l8;
        }
        const char* buf = (const char*)lds + (ch & 1) * 16384;
#pragma unroll
        for (int kstep = 0; kstep < 2; ++kstep) {
            int g = kstep * 4 + lg;
#pragma unroll
            for (int nt = 0; nt < 4; ++nt) {
                int nrow = nt * 16 + ln;
                bf16x8 bh = *(const bf16x8*)(buf + (g * 64 + nrow) * 16);
                bf16x8 bl = *(const bf16x8*)(buf + 8192 + (g * 64 + nrow) * 16);
                acc[nt] = __builtin_amdgcn_mfma_f32_16x16x32_bf16(ah[kstep], bh, acc[nt], 0, 0, 0);
                acc[nt] = __builtin_amdgcn_mfma_f32_16x16x32_bf16(ah[kstep], bl, acc[nt], 0, 0, 0);
                acc[nt] = __builtin_amdgcn_mfma_f32_16x16x32_bf16(al[kstep], bh, acc[nt], 0, 0, 0);
            }
        }
#pragma unroll
        for (int i = 0; i < 4; ++i) xc[i] = xn[i];
    }
#pragma unroll
    for (int nt = 0; nt < 4; ++nt)
#pragma unroll
        for (int r = 0; r < 4; ++r)
            partA[((size_t)ks * 1024 + row0 + w * 16 + lg * 4 + r) * 64 + nt * 16 + ln] =
                acc[nt][r];
}

// ---------------------------------------------------------------------------
// reduceA: h1[row,d] = relu(sum_s partA + b_emb[d]) + pe1[l,d]; s1[row]=sum_d h1
__global__ __launch_bounds__(64) void reduceA_kernel(const float* __restrict__ partA,
                                                     const float* __restrict__ bemb,
                                                     const float* __restrict__ pe1,
                                                     float* __restrict__ h1,
                                                     float* __restrict__ s1) {
    int row = blockIdx.x;
    int d = threadIdx.x;
    int l = row & 127;
    float v = bemb[d];
#pragma unroll 5
    for (int s = 0; s < SPLITS_; ++s) v += partA[((size_t)s * 1024 + row) * 64 + d];
    v = fmaxf(v, 0.f) + pe1[l * 64 + d];
    h1[row * 64 + d] = v;
    float sum = v;
    for (int off = 32; off > 0; off >>= 1) sum += __shfl_down(sum, off);
    if (d == 0) s1[row] = sum;
}

// ---------------------------------------------------------------------------
// wr1: Wr1[b,r,j] = sum_k s1[b,k] * W_red[r, k*64+j]
__global__ __launch_bounds__(64) void wr1_kernel(const float* __restrict__ Wred,
                                                 const float* __restrict__ s1,
                                                 float* __restrict__ Wr1) {
    __shared__ float ss[8 * 128];
    int r = blockIdx.x;
    int j = threadIdx.x;
    for (int idx = j; idx < 1024; idx += 64) ss[idx] = s1[idx];
    __syncthreads();
    float acc[8];
#pragma unroll
    for (int b = 0; b < 8; ++b) acc[b] = 0.f;
    const float* w = Wred + (size_t)r * 8192 + j;
    for (int k = 0; k < 128; ++k) {
        float wv = w[k * 64];
#pragma unroll
        for (int b = 0; b < 8; ++b) acc[b] = fmaf(ss[b * 128 + k], wv, acc[b]);
    }
#pragma unroll
    for (int b = 0; b < 8; ++b) Wr1[((size_t)b * 128 + r) * 64 + j] = acc[b];
}

// ---------------------------------------------------------------------------
// h2: h2[b,i,r] = relu(sum_j h1[b,i,j]*Wr1[b,r,j] + b_red[r]) + pe2[i,r]; s2=sum_r
__global__ __launch_bounds__(128) void h2_kernel(const float* __restrict__ h1,
                                                 const float* __restrict__ Wr1,
                                                 const float* __restrict__ bred,
                                                 const float* __restrict__ pe2,
                                                 float* __restrict__ h2,
                                                 float* __restrict__ s2) {
    __shared__ float hrow[64];
    __shared__ float red[2];
    int row = blockIdx.x;
    int b = row >> 7, i = row & 127;
    int r = threadIdx.x;
    if (r < 64) hrow[r] = h1[row * 64 + r];
    __syncthreads();
    float acc = bred[r];
    const float4* w = (const float4*)(Wr1 + ((size_t)b * 128 + r) * 64);
#pragma unroll
    for (int j4 = 0; j4 < 16; ++j4) {
        float4 wv = w[j4];
        float4 hv = *(const float4*)&hrow[j4 * 4];
        acc = fmaf(hv.x, wv.x, acc);
        acc = fmaf(hv.y, wv.y, acc);
        acc = fmaf(hv.z, wv.z, acc);
        acc = fmaf(hv.w, wv.w, acc);
    }
    float val = fmaxf(acc, 0.f) + pe2[i * 128 + r];
    h2[row * 128 + r] = val;
    float sum = val;
    for (int off = 32; off > 0; off >>= 1) sum += __shfl_down(sum, off);
    if ((r & 63) == 0) red[r >> 6] = sum;
    __syncthreads();
    if (r == 0) s2[row] = red[0] + red[1];
}

// ---------------------------------------------------------------------------
// wr2: Wr2[b,r2,j] = sum_k s2[b,k] * W_red2[r2, k*128+j]
__global__ __launch_bounds__(128) void wr2_kernel(const float* __restrict__ Wred2,
                                                  const float* __restrict__ s2,
                                                  float* __restrict__ Wr2) {
    __shared__ float ss[8 * 128];
    int r = blockIdx.x;
    int j = threadIdx.x;
    for (int idx = j; idx < 1024; idx += 128) ss[idx] = s2[idx];
    __syncthreads();
    float acc[8];
#pragma unroll
    for (int b = 0; b < 8; ++b) acc[b] = 0.f;
    const float* w = Wred2 + (size_t)r * 16384 + j;
    for (int k = 0; k < 128; ++k) {
        float wv = w[k * 128];
#pragma unroll
        for (int b = 0; b < 8; ++b) acc[b] = fmaf(ss[b * 128 + k], wv, acc[b]);
    }
#pragma unroll
    for (int b = 0; b < 8; ++b) Wr2[((size_t)b * 320 + r) * 128 + j] = acc[b];
}

// ---------------------------------------------------------------------------
// h3: h3[b,i,r2] = relu(sum_j h2[b,i,j]*Wr2[b,r2,j] + b_red2[r2]) + pe3[i,r2]
__global__ __launch_bounds__(320) void h3_kernel(const float* __restrict__ h2,
                                                 const float* __restrict__ Wr2,
                                                 const float* __restrict__ bred2,
                                                 const float* __restrict__ pe3,
                                                 float* __restrict__ h3) {
    __shared__ float hrow[128];
    int row = blockIdx.x;
    int b = row >> 7, i = row & 127;
    int r = threadIdx.x;
    if (r < 128) hrow[r] = h2[row * 128 + r];
    __syncthreads();
    float acc = bred2[r];
    const float4* w = (const float4*)(Wr2 + ((size_t)b * 320 + r) * 128);
#pragma unroll
    for (int j4 = 0; j4 < 32; ++j4) {
        float4 wv = w[j4];
        float4 hv = *(const float4*)&hrow[j4 * 4];
        acc = fmaf(hv.x, wv.x, acc);
        acc = fmaf(hv.y, wv.y, acc);
        acc = fmaf(hv.z, wv.z, acc);
        acc = fmaf(hv.w, wv.w, acc);
    }
    h3[(size_t)row * 320 + r] = fmaxf(acc, 0.f) + pe3[i * 320 + r];
}

// ---------------------------------------------------------------------------
// h4 v3: grid (256 rowgroups of 4, 2 u-halves), block 320 (thread = one u).
// Wup1 natural layout: per-thread row reads are contiguous float4 (L2-resident);
// h3 rows transposed into LDS for broadcast float4 reads.
__global__ __launch_bounds__(320) void h4_kernel(const float* __restrict__ h3,
                                                 const float* __restrict__ Wup1,
                                                 const float* __restrict__ bup1,
                                                 unsigned short* __restrict__ h4b) {
    __shared__ float hsT[320 * 4];
    int t = threadIdx.x;
    int row0 = blockIdx.x * 4;
    int u = blockIdx.y * 320 + t;
    for (int idx = t; idx < 1280; idx += 320) {
        int q = idx / 320, j = idx - q * 320;
        hsT[j * 4 + q] = h3[(size_t)(row0 + q) * 320 + j];
    }
    __syncthreads();
    float acc[4] = {0.f, 0.f, 0.f, 0.f};
    const float4* w = (const float4*)(Wup1 + (size_t)u * 320);
#pragma unroll 2
    for (int j4 = 0; j4 < 80; ++j4) {
        float4 wv = w[j4];
#pragma unroll
        for (int e = 0; e < 4; ++e) {
            float wc = (e == 0) ? wv.x : (e == 1) ? wv.y : (e == 2) ? wv.z : wv.w;
            float4 hv = *(const float4*)&hsT[(j4 * 4 + e) * 4];
            acc[0] = fmaf(hv.x, wc, acc[0]);
            acc[1] = fmaf(hv.y, wc, acc[1]);
            acc[2] = fmaf(hv.z, wc, acc[2]);
            acc[3] = fmaf(hv.w, wc, acc[3]);
        }
    }
    float bias = bup1[u];
#pragma unroll
    for (int q = 0; q < 4; ++q)
        h4b[(size_t)(row0 + q) * 640 + u] = f2bf(fmaxf(acc[q] + bias, 0.f));
}

// ---------------------------------------------------------------------------
// final MFMA kernel, 2-batch tile: 128v x (2b x 128l), 512 thr (8 waves), BK=64.
// LDS: A 16 KB + B0 16 KB + B1 16 KB (swizzled rows as before). 3 blocks/CU.
// out[b,v] = relu(bfin + sum_l Wfin[l]*relu(bup2[v] + sum_u h4[b,l,u]*Wup2[v,u]))
__global__ __launch_bounds__(512) void final_mfma_kernel(
    const unsigned short* __restrict__ h4b,
    const unsigned short* __restrict__ Wup2b,
    const float* __restrict__ bup2,
    const float* __restrict__ Wfin,
    const float* __restrict__ bfin,
    float* __restrict__ out) {
    __shared__ short tile[24576];          // 48 KB: A | B0 | B1
    __shared__ float redbuf[2][2][128];    // [b_local][l_half][v]

    int t = threadIdx.x;
    int lane = t & 63;
    int w = t >> 6;                 // 0..7
    int wv = w >> 2;                // v-half 0..1
    int wq = w & 3;                 // n-quadrant: b_local = wq>>1, l_half = wq&1
    int bl_ = wq >> 1, lh = wq & 1;
    int ln = lane & 15, lg = lane >> 4;
    int b0 = blockIdx.y * 2;
    int v0 = blockIdx.x * 128;

    f32x4 acc[4][4];
#pragma unroll
    for (int mt = 0; mt < 4; ++mt)
#pragma unroll
        for (int nt = 0; nt < 4; ++nt) acc[mt][nt] = (f32x4){0.f, 0.f, 0.f, 0.f};

    for (int ch = 0; ch < 10; ++ch) {
        int k0 = ch * 64;
        __syncthreads();
#pragma unroll
        for (int s = 0; s < 6; ++s) {
            int F = (w * 6 + s) * 1024 + lane * 16;    // byte offset in 48 KB
            int region = F >> 14;                       // 0=A, 1=B0, 2=B1
            int rr = (F >> 7) & 127;                    // row within region
            int g = ((F >> 4) & 7) ^ (rr & 7);          // logical k-block
            size_t rowG = (region == 0) ? (size_t)(v0 + rr)
                                        : (size_t)((b0 + region - 1) * 128 + rr);
            const unsigned short* base = (region == 0) ? Wup2b : h4b;
            const char* gp = (const char*)base + (rowG * 640 + (size_t)(k0 + g * 8)) * 2;
            char* lp = (char*)tile + (w * 6 + s) * 1024;   // wave-uniform
            GLDS16(gp, lp);
        }
        __syncthreads();
#pragma unroll
        for (int ks = 0; ks < 2; ++ks) {
            bf16x8 aF[4], bF[4];
#pragma unroll
            for (int mt = 0; mt < 4; ++mt) {
                int rA = wv * 64 + mt * 16 + ln;
                int g = ks * 4 + lg;
                int off = rA * 128 + ((g ^ (rA & 7)) * 16);
                aF[mt] = *(const bf16x8*)((const char*)tile + off);
            }
#pragma unroll
            for (int nt = 0; nt < 4; ++nt) {
                int rB = lh * 64 + nt * 16 + ln;
                int g = ks * 4 + lg;
                int off = (1 + bl_) * 16384 + rB * 128 + ((g ^ (rB & 7)) * 16);
                bF[nt] = *(const bf16x8*)((const char*)tile + off);
            }
#pragma unroll
            for (int mt = 0; mt < 4; ++mt)
#pragma unroll
                for (int nt = 0; nt < 4; ++nt)
                    acc[mt][nt] = __builtin_amdgcn_mfma_f32_16x16x32_bf16(
                        aF[mt], bF[nt], acc[mt][nt], 0, 0, 0);
        }
    }

    // Epilogue: C/D layout col(l)=lane&15, row(v)=(lane>>4)*4+reg
    float bfin0 = bfin[0];
#pragma unroll
    for (int mt = 0; mt < 4; ++mt) {
        float bu[4];
#pragma unroll
        for (int r = 0; r < 4; ++r)
            bu[r] = bup2[v0 + wv * 64 + mt * 16 + lg * 4 + r];
        float part[4] = {0.f, 0.f, 0.f, 0.f};
#pragma unroll
        for (int nt = 0; nt < 4; ++nt) {
            float wf = Wfin[lh * 64 + nt * 16 + ln];
#pragma unroll
            for (int r = 0; r < 4; ++r)
                part[r] += wf * fmaxf(acc[mt][nt][r] + bu[r], 0.f);
        }
#pragma unroll
        for (int off = 8; off >= 1; off >>= 1)
#pragma unroll
            for (int r = 0; r < 4; ++r) part[r] += __shfl_xor(part[r], off, 64);
        if (ln == 0) {
#pragma unroll
            for (int r = 0; r < 4; ++r)
                redbuf[bl_][lh][wv * 64 + mt * 16 + lg * 4 + r] = part[r];
        }
    }
    __syncthreads();
    if (t < 256) {
        int bb = t >> 7, v = t & 127;
        float vsum = redbuf[bb][0][v] + redbuf[bb][1][v] + bfin0;
        out[(size_t)(b0 + bb) * 32000 + v0 + v] = fmaxf(vsum, 0.f);
    }
}

// ---------------------------------------------------------------------------
extern "C" void kernel_launch(void* const* d_in, const int* in_sizes, int n_in,
                              void* d_out, int out_size, void* d_ws, size_t ws_size,
                              hipStream_t stream) {
    const float* x      = (const float*)d_in[0];
    const float* W_emb  = (const float*)d_in[1];
    const float* b_emb  = (const float*)d_in[2];
    const float* W_pos1 = (const float*)d_in[3];
    const float* b_pos1 = (const float*)d_in[4];
    const float* W_red  = (const float*)d_in[5];
    const float* b_red  = (const float*)d_in[6];
    const float* W_pos2 = (const float*)d_in[7];
    const float* b_pos2 = (const float*)d_in[8];
    const float* W_red2 = (const float*)d_in[9];
    const float* b_red2 = (const float*)d_in[10];
    const float* W_pos3 = (const float*)d_in[11];
    const float* b_pos3 = (const float*)d_in[12];
    const float* W_up1  = (const float*)d_in[13];
    const float* b_up1  = (const float*)d_in[14];
    const float* W_up2  = (const float*)d_in[15];
    const float* b_up2  = (const float*)d_in[16];
    const float* W_fin  = (const float*)d_in[17];
    const float* b_fin  = (const float*)d_in[18];
    float* out = (float*)d_out;

    float* ws  = (float*)d_ws;
    float* pe1 = ws;                 // 8192
    float* pe2 = pe1 + 8192;         // 16384
    float* pe3 = pe2 + 16384;        // 40960
    float* h1  = pe3 + 40960;        // 65536
    float* s1  = h1 + 65536;         // 1024
    float* Wr1 = s1 + 1024;          // 65536
    float* h2  = Wr1 + 65536;        // 131072
    float* s2  = h2 + 131072;        // 1024
    float* Wr2 = s2 + 1024;          // 327680
    float* h3  = Wr2 + 327680;       // 327680
    unsigned short* h4b   = (unsigned short*)(h3 + 327680);          // 655360 shorts
    unsigned short* Wup2b = (unsigned short*)((float*)h4b + 327680); // 20,480,000 shorts
    float* after = (float*)Wup2b + 10240000;
    unsigned short* Whb = (unsigned short*)after;             // 2,048,000 shorts
    unsigned short* Wlb = Whb + 2048000;                      // 2,048,000 shorts
    // partA (50*1024*64 = 3.28M floats = 13.1 MB) aliases the Wup2b region:
    // dead after reduceA; prep_weights writes Wup2b BEFORE embA -> move prep's
    // Wup2b target... NOTE: prep_weights writes Wup2b first, so partA must NOT
    // alias it. Place partA after Whb/Wlb instead.
    float* partA = (float*)(Wlb + 2048000);                   // 3,276,800 floats
    // total ws use ~73 MB (< 512 MB ws)

    prep_weights<<<dim3(5096), 256, 0, stream>>>(W_emb, Whb, Wlb, W_up2, Wup2b);
    pe_all<<<dim3(128, 3), 320, 0, stream>>>(W_pos1, b_pos1, pe1, W_pos2, b_pos2,
                                             pe2, W_pos3, b_pos3, pe3);
    embA_mfma<<<dim3(16, SPLITS_), 256, 0, stream>>>(x, Whb, Wlb, partA);
    reduceA_kernel<<<dim3(1024), 64, 0, stream>>>(partA, b_emb, pe1, h1, s1);
    wr1_kernel<<<dim3(128), 64, 0, stream>>>(W_red, s1, Wr1);
    h2_kernel<<<dim3(1024), 128, 0, stream>>>(h1, Wr1, b_red, pe2, h2, s2);
    wr2_kernel<<<dim3(320), 128, 0, stream>>>(W_red2, s2, Wr2);
    h3_kernel<<<dim3(1024), 320, 0, stream>>>(h2, Wr2, b_red2, pe3, h3);
    h4_kernel<<<dim3(256, 2), 320, 0, stream>>>(h3, W_up1, b_up1, h4b);
    final_mfma_kernel<<<dim3(250, 4), 512, 0, stream>>>(h4b, Wup2b, b_up2, W_fin,
                                                        b_fin, out);
}